// Round 13
// baseline (49.326 us; speedup 1.0000x reference)
//
#include <hip/hip_runtime.h>
#include <hip/hip_bf16.h>
#include <stdint.h>

// Problem constants
#define BB 64      // batch
#define LL 256     // x seq len
#define TT 64      // y seq len
#define DD 512     // input dim
#define EE 200     // embed dim
#define EP 208     // embed dim padded to 13*16 (32x32x16 MFMA K-granularity)
#define NKK 13     // K-steps in pair kernel (EP/16)
#define NROWS_X 16384   // 64*256
// Fragment-chunk layout: 1 chunk = 32 rows x 16 e = 64 lanes x 16 B = 1024 B.
// lane l holds row (l&31), e_local (l>>5)*8 .. +8, at shorts chunk*512 + l*8.
// Unified pT: chunk index = (global_row >> 5)*13 + n (x rows first, then y).
#define BSTRIDE 264                // proj bounce row stride in shorts

typedef __attribute__((ext_vector_type(8))) short short8;
typedef __attribute__((ext_vector_type(4))) float floatx4;
typedef __attribute__((ext_vector_type(16))) float floatx16;

__device__ __forceinline__ short f2bf(float f) {
  uint32_t u = __builtin_bit_cast(uint32_t, f);
  u = (u + 0x7fffu + ((u >> 16) & 1u)) >> 16;  // RNE
  return (short)u;
}

__device__ __forceinline__ uint32_t pack2(float lo, float hi) {
  return __builtin_amdgcn_perm(__builtin_bit_cast(uint32_t, hi),
                               __builtin_bit_cast(uint32_t, lo), 0x07060302u);
}

typedef const __attribute__((address_space(1))) uint32_t gu32_t;
typedef __attribute__((address_space(3))) uint32_t lu32_t;
__device__ __forceinline__ void glds16(const void* g, void* l) {
  __builtin_amdgcn_global_load_lds((gu32_t*)g, (lu32_t*)l, 16, 0, 0);
}

// counted-vmcnt barrier: wait until only the newest N vmem ops remain, then barrier.
// vmcnt retires in issue order (m135), so vmcnt(6) with stage(s+1)'s 6 glds in
// flight guarantees stage(s) is fully landed in LDS.
#define VMCNT_BARRIER(N) asm volatile("s_waitcnt vmcnt(" #N ")\n\ts_barrier" ::: "memory")

// ---------------- Kernel 0: W (200x512 f32) -> Wb (208x512 bf16, zero-padded), RNE
__global__ void wcvt_kernel(const float* __restrict__ W, short* __restrict__ Wb) {
  const int t = blockIdx.x * 256 + threadIdx.x;   // 0 .. 13311
  const int base = t * 8;
  const int e = base >> 9;
  short8 o;
  if (e < EE) {
    const floatx4 f0 = *(const floatx4*)(W + base);
    const floatx4 f1 = *(const floatx4*)(W + base + 4);
    o[0] = f2bf(f0.x); o[1] = f2bf(f0.y); o[2] = f2bf(f0.z); o[3] = f2bf(f0.w);
    o[4] = f2bf(f1.x); o[5] = f2bf(f1.y); o[6] = f2bf(f1.z); o[7] = f2bf(f1.w);
  } else {
    o = (short8)0;
  }
  *(short8*)(Wb + base) = o;
}

// ---------------- Kernel 1: projection GEMM -> fragment-layout pT
// R7 pipeline restored: BM=64, grid 320, TRIPLE-buffered glds staging with
// counted vmcnt(6) barriers (depth-2 in flight: ~43 KB/block vs ~9.2 KB/CU
// needed for HBM latency-BW product). Stage = exactly 6 glds/thread uniform
// (A 2 + B 4, B rows 208..255 clamped). B bank swizzle fixed per R11 counters:
// col ^ ((row>>1)&3) -> 16-lane read groups span all 32 banks (2-way = free).
__global__ __launch_bounds__(256, 2) void proj_kernel(const float* __restrict__ x,
                                                      const float* __restrict__ y,
                                                      const short* __restrict__ Wb,
                                                      const float* __restrict__ bias,
                                                      short* __restrict__ pT) {
  __shared__ __align__(16) char smem[73728];
  float* ldsA = (float*)smem;               // [3][64*32]  f32   24,576 B
  short* ldsB = (short*)(smem + 24576);     // [3][256*32] bf16  49,152 B
  short* bounce = (short*)smem;             // [64][BSTRIDE] 33,792 B (after loop)

  const int tid  = threadIdx.x;
  const int lane = tid & 63;
  const int wid  = tid >> 6;
  const int r16   = lane & 15;
  const int khalf = lane >> 4;        // 0..3

  const int row0 = blockIdx.x * 64;
  const float* srcbase = (row0 < NROWS_X) ? (x + (size_t)row0 * DD)
                                          : (y + (size_t)(row0 - NROWS_X) * DD);

  floatx4 acc[NKK];
#pragma unroll
  for (int n = 0; n < NKK; n++) acc[n] = (floatx4){0.f, 0.f, 0.f, 0.f};

  // Stage K-step ks into buffer buf (exactly 6 glds per thread, wave-uniform).
  // ldsA[r][c16] <- x[r][ks*32 + (c^(r&7))*4 ..+4)
  // ldsB[r][c16] <- Wb[min(r,207)][ks*32 + (c^((r>>1)&3))*8 ..+8)
  auto stage = [&](int buf, int ks) {
#pragma unroll
    for (int it = 0; it < 2; it++) {
      const int p = it * 256 + tid;
      const int r = p >> 3, c = p & 7;
      glds16(srcbase + (size_t)r * DD + ks * 32 + ((c ^ (r & 7)) << 2),
             &ldsA[buf * 2048 + p * 4]);
    }
#pragma unroll
    for (int it = 0; it < 4; it++) {
      const int p = it * 256 + tid;
      const int r = p >> 2, c = p & 3;
      const int sr = (r < EP) ? r : (EP - 1);   // rows 208..255: dup, never read
      glds16(Wb + (size_t)sr * DD + ks * 32 + ((c ^ ((sr >> 1) & 3)) << 3),
             &ldsB[buf * 8192 + p * 8]);
    }
  };

  auto compute = [&](int s) {
    const int buf = s % 3;
    const int r = wid * 16 + r16;
    const int c0 = (2 * khalf) ^ (r16 & 7);         // (r&7)==(r16&7): 16|8
    const int c1 = (2 * khalf + 1) ^ (r16 & 7);
    const floatx4 f0 = *(const floatx4*)&ldsA[buf * 2048 + r * 32 + c0 * 4];
    const floatx4 f1 = *(const floatx4*)&ldsA[buf * 2048 + r * 32 + c1 * 4];
    union { short8 s8; uint32_t u[4]; } af;
    af.u[0] = pack2(f0.x, f0.y);
    af.u[1] = pack2(f0.z, f0.w);
    af.u[2] = pack2(f1.x, f1.y);
    af.u[3] = pack2(f1.z, f1.w);
    const int bcol = (khalf ^ ((r16 >> 1) & 3)) << 3;  // (erow>>1)&3 == (r16>>1)&3
#pragma unroll
    for (int n = 0; n < NKK; n++) {
      const int erow = n * 16 + r16;
      const short8 bfrag = *(const short8*)&ldsB[buf * 8192 + erow * 32 + bcol];
      acc[n] = __builtin_amdgcn_mfma_f32_16x16x32_bf16(af.s8, bfrag, acc[n], 0, 0, 0);
    }
  };

  stage(0, 0);
  stage(1, 1);

  for (int s = 0; s < 15; s++) {
    VMCNT_BARRIER(6);                 // stage(s) landed; stage(s+1) still in flight
    if (s + 2 < 16) stage((s + 2) % 3, s + 2);  // buf (s+2)%3: readers finished at
                                                // barrier s (they read it as s-1)
    compute(s);
  }
  VMCNT_BARRIER(0);                   // drain stage(15)
  compute(15);

  __syncthreads();   // all LDS reads done; safe to reuse smem as bounce

  // Epilogue 1: bias + f2bf -> bounce[lr][e]
#pragma unroll
  for (int n = 0; n < NKK; n++) {
    const int e = n * 16 + r16;
    const float bv = (e < EE) ? bias[e] : 0.0f;
#pragma unroll
    for (int rr = 0; rr < 4; rr++) {
      const int lr = wid * 16 + khalf * 4 + rr;
      bounce[lr * BSTRIDE + e] = f2bf(acc[n][rr] + bv);
    }
  }
  __syncthreads();

  // Epilogue 2: 26 chunks x 64 pieces = 1664 16B pieces, coalesced stores.
  const int rowblk0 = blockIdx.x * 2;
  for (int c = tid; c < 1664; c += 256) {
    const int q  = c >> 6;
    const int mt = (q >= 13) ? 1 : 0;
    const int n  = q - mt * 13;
    const int l  = c & 63;
    const int lr = mt * 32 + (l & 31);
    const short8 piece = *(const short8*)&bounce[lr * BSTRIDE + n * 16 + (l >> 5) * 8];
    *(short8*)&pT[((size_t)((rowblk0 + mt) * 13 + n)) * 512 + l * 8] = piece;
  }
}

// ---------------- Kernel 2: pair kernel — A-in-registers, B-in-LDS (R10, unchanged)
__global__ __launch_bounds__(512, 2) void pair_kernel(const short* __restrict__ xpT,
                                                      const short* __restrict__ ypT,
                                                      float* __restrict__ S) {
  __shared__ __align__(16) char lds[2 * 53248 + 16384];
  float* red = (float*)(lds + 2 * 53248);   // [j 0..15][wj 0..3][64 t] = 16 KB

  const int tid  = threadIdx.x;
  const int lane = tid & 63;
  const int wid  = tid >> 6;       // 0..7
  const int jj2  = wid >> 2;       // j-slot within 2-j group
  const int wj   = wid & 3;        // lt-pair
  const int bid  = blockIdx.x;
  const int i    = bid & 63;
  const int jq   = bid >> 6;
  const int jbase = jq * 16;

  // A global->reg: 2 L-tiles x 13 kk fragments
  short8 a0[NKK], a1[NKK];
  {
    const short* ab0 = xpT + ((size_t)((i * 8 + wj * 2 + 0) * NKK)) * 512 + lane * 8;
    const short* ab1 = xpT + ((size_t)((i * 8 + wj * 2 + 1) * NKK)) * 512 + lane * 8;
#pragma unroll
    for (int kk = 0; kk < NKK; kk++) {
      a0[kk] = *(const short8*)(ab0 + kk * 512);
      a1[kk] = *(const short8*)(ab1 + kk * 512);
    }
  }

  auto stageB = [&](int g) {
    const short* src = ypT + (size_t)(jbase + g * 2) * 26 * 512;
    char* dst = lds + (g & 1) * 53248;
    for (int c = tid; c < 3328; c += 512)
      glds16(src + (size_t)c * 8, dst + c * 16);
  };

  stageB(0);
  __syncthreads();

  for (int g = 0; g < 8; g++) {
    if (g + 1 < 8) stageB(g + 1);

    const int j = g * 2 + jj2;
    const short* bbase = (const short*)(lds + (g & 1) * 53248) +
                         (size_t)(jj2 * 26 * 512) + lane * 8;

    floatx16 accA0n0, accA0n1, accA1n0, accA1n1;
#pragma unroll
    for (int r = 0; r < 16; r++) {
      accA0n0[r] = 0.f; accA0n1[r] = 0.f; accA1n0[r] = 0.f; accA1n1[r] = 0.f;
    }

#pragma unroll
    for (int kk = 0; kk < NKK; kk++) {
      const short8 b0 = *(const short8*)(bbase + (0 * NKK + kk) * 512);
      const short8 b1 = *(const short8*)(bbase + (1 * NKK + kk) * 512);
      accA0n0 = __builtin_amdgcn_mfma_f32_32x32x16_bf16(a0[kk], b0, accA0n0, 0, 0, 0);
      accA1n0 = __builtin_amdgcn_mfma_f32_32x32x16_bf16(a1[kk], b0, accA1n0, 0, 0, 0);
      accA0n1 = __builtin_amdgcn_mfma_f32_32x32x16_bf16(a0[kk], b1, accA0n1, 0, 0, 0);
      accA1n1 = __builtin_amdgcn_mfma_f32_32x32x16_bf16(a1[kk], b1, accA1n1, 0, 0, 0);
    }

    float v0 = accA0n0[0], v1 = accA0n1[0];
#pragma unroll
    for (int r = 0; r < 16; r++) {
      v0 = fmaxf(v0, accA0n0[r]); v0 = fmaxf(v0, accA1n0[r]);
      v1 = fmaxf(v1, accA0n1[r]); v1 = fmaxf(v1, accA1n1[r]);
    }
    v0 = fmaxf(v0, __shfl_xor(v0, 32, 64));
    v1 = fmaxf(v1, __shfl_xor(v1, 32, 64));
    if (lane < 32) {
      red[(j * 4 + wj) * 64 + 0 * 32 + lane] = v0;
      red[(j * 4 + wj) * 64 + 1 * 32 + lane] = v1;
    }

    __syncthreads();
  }

  // Final: wave w reduces j = 2w, 2w+1
#pragma unroll
  for (int rep = 0; rep < 2; rep++) {
    const int j = wid * 2 + rep;
    const int t = lane;
    float v = red[(j * 4 + 0) * 64 + t];
    v = fmaxf(v, red[(j * 4 + 1) * 64 + t]);
    v = fmaxf(v, red[(j * 4 + 2) * 64 + t]);
    v = fmaxf(v, red[(j * 4 + 3) * 64 + t]);
    v += __shfl_xor(v, 1, 64);
    v += __shfl_xor(v, 2, 64);
    v += __shfl_xor(v, 4, 64);
    v += __shfl_xor(v, 8, 64);
    v += __shfl_xor(v, 16, 64);
    v += __shfl_xor(v, 32, 64);
    if (t == 0) S[i * BB + jbase + j] = v * (1.0f / 64.0f);
  }
}

extern "C" void kernel_launch(void* const* d_in, const int* in_sizes, int n_in,
                              void* d_out, int out_size, void* d_ws, size_t ws_size,
                              hipStream_t stream) {
  const float* x = (const float*)d_in[0];   // 64*256*512
  const float* y = (const float*)d_in[1];   // 64*64*512
  const float* W = (const float*)d_in[2];   // 200*512
  const float* b = (const float*)d_in[3];   // 200
  float* S = (float*)d_out;                 // 64*64

  char* ws = (char*)d_ws;
  short* Wb = (short*)ws;                   // 208*512*2 = 212,992 B
  short* pT = (short*)(ws + 262144);        // 8320 chunks * 1024 B = 8,519,680 B
  short* ypT = pT + (size_t)6656 * 512;     // y starts at chunk 6656

  wcvt_kernel<<<52, 256, 0, stream>>>(W, Wb);
  proj_kernel<<<320, 256, 0, stream>>>(x, y, Wb, b, pT);
  pair_kernel<<<256, 512, 0, stream>>>(pT, ypT, S);
}

// Round 15
// 45.431 us; speedup vs baseline: 1.0857x; 1.0857x over previous
//
#include <hip/hip_runtime.h>
#include <hip/hip_bf16.h>
#include <stdint.h>

// Problem constants
#define BB 64      // batch
#define LL 256     // x seq len
#define TT 64      // y seq len
#define DD 512     // input dim
#define EE 200     // embed dim
#define EP 208     // embed dim padded to 13*16
#define NKK 13     // K-steps in pair kernel (EP/16)
#define NROWS_X 16384   // 64*256
// Fragment-chunk layout: 1 chunk = 32 rows x 16 e = 64 lanes x 16 B = 1024 B.
// lane l holds row (l&31), e_local (l>>5)*8 .. +8, at shorts chunk*512 + l*8.
// Unified pT: chunk index = (global_row >> 5)*13 + n (x rows first, then y).
#define BSTRIDE 264                // proj bounce row stride in shorts
#define PBM 80                     // proj rows per block: 20480/80 = 256 = exact grid

typedef __attribute__((ext_vector_type(8))) short short8;
typedef __attribute__((ext_vector_type(4))) float floatx4;
typedef __attribute__((ext_vector_type(16))) float floatx16;

__device__ __forceinline__ short f2bf(float f) {
  uint32_t u = __builtin_bit_cast(uint32_t, f);
  u = (u + 0x7fffu + ((u >> 16) & 1u)) >> 16;  // RNE
  return (short)u;
}

__device__ __forceinline__ uint32_t pack2(float lo, float hi) {
  return __builtin_amdgcn_perm(__builtin_bit_cast(uint32_t, hi),
                               __builtin_bit_cast(uint32_t, lo), 0x07060302u);
}

typedef const __attribute__((address_space(1))) uint32_t gu32_t;
typedef __attribute__((address_space(3))) uint32_t lu32_t;
__device__ __forceinline__ void glds16(const void* g, void* l) {
  __builtin_amdgcn_global_load_lds((gu32_t*)g, (lu32_t*)l, 16, 0, 0);
}

// counted-vmcnt barrier: vmcnt retires in issue order; waiting to N guarantees
// everything older than the newest N ops has landed.
#define VMCNT_BARRIER(N) asm volatile("s_waitcnt vmcnt(" #N ") lgkmcnt(0)\n\ts_barrier" ::: "memory")

// ---------------- Kernel 0: W (200x512 f32) -> Wb (208x512 bf16, zero-padded), RNE
__global__ void wcvt_kernel(const float* __restrict__ W, short* __restrict__ Wb) {
  const int t = blockIdx.x * 256 + threadIdx.x;   // 0 .. 13311
  const int base = t * 8;
  const int e = base >> 9;
  short8 o;
  if (e < EE) {
    const floatx4 f0 = *(const floatx4*)(W + base);
    const floatx4 f1 = *(const floatx4*)(W + base + 4);
    o[0] = f2bf(f0.x); o[1] = f2bf(f0.y); o[2] = f2bf(f0.z); o[3] = f2bf(f0.w);
    o[4] = f2bf(f1.x); o[5] = f2bf(f1.y); o[6] = f2bf(f1.z); o[7] = f2bf(f1.w);
  } else {
    o = (short8)0;
  }
  *(short8*)(Wb + base) = o;
}

// ---------------- Kernel 1: projection GEMM -> fragment-layout pT
// BM=80, grid 256 EXACT (1 block/CU — testing the grid-imbalance theory).
// 320 thr = 5 waves x (16 rows x 208 E). Triple-buffered glds staging with
// counted vmcnt barriers. B-stage tail handled by WAVE-UNIFORM predicate
// (tid<192 = waves 0-2) so every glds dst run stays lane-linear (rule #21;
// R14's dst-clamp corrupted LDS). Per-wave stage counts: 5 (waves 0-2) /
// 4 (waves 3-4) -> barrier uses vmcnt(4).
__global__ __launch_bounds__(320, 1) void proj_kernel(const float* __restrict__ x,
                                                      const float* __restrict__ y,
                                                      const short* __restrict__ Wb,
                                                      const float* __restrict__ bias,
                                                      short* __restrict__ pT) {
  __shared__ __align__(16) char smem[71680];
  float* ldsA = (float*)smem;               // [3][80*32] f32  30,720 B
  short* ldsB = (short*)(smem + 30720);     // [3][208*32] bf16 39,936 B
  short* bounce = (short*)smem;             // [80][BSTRIDE] 42,240 B (after loop)

  const int tid  = threadIdx.x;
  const int lane = tid & 63;
  const int wid  = tid >> 6;          // 0..4
  const int r16   = lane & 15;
  const int khalf = lane >> 4;        // 0..3

  const int row0 = blockIdx.x * PBM;

  floatx4 acc[NKK];
#pragma unroll
  for (int n = 0; n < NKK; n++) acc[n] = (floatx4){0.f, 0.f, 0.f, 0.f};

  // Stage K-step ks into buffer buf.
  // A: 640 chunks (80 rows x 8): ldsA[r][c16] <- src(r)[ks*32 + (c^(r&7))*4]
  // B: 832 chunks (208 rows x 4): ldsB[r][c16] <- Wb[r][ks*32 + (c^((r>>1)&3))*8]
  //    its 0,1 cover 0..639 (all threads); it 2 covers 640..831 (waves 0-2 only).
  auto stage = [&](int buf, int ks) {
#pragma unroll
    for (int it = 0; it < 2; it++) {
      const int p = it * 320 + tid;
      const int r = p >> 3, c = p & 7;
      const int gr = row0 + r;
      const float* src = (gr < NROWS_X) ? (x + (size_t)gr * DD)
                                        : (y + (size_t)(gr - NROWS_X) * DD);
      glds16(src + ks * 32 + ((c ^ (r & 7)) << 2),
             &ldsA[buf * 2560 + p * 4]);
    }
#pragma unroll
    for (int it = 0; it < 3; it++) {
      const int p = it * 320 + tid;
      if (it < 2 || tid < 192) {        // wave-uniform: it==2 -> waves 0,1,2 only
        const int r = p >> 2, c = p & 3;
        glds16(Wb + (size_t)r * DD + ks * 32 + ((c ^ ((r >> 1) & 3)) << 3),
               &ldsB[buf * 6656 + p * 8]);
      }
    }
  };

  auto compute = [&](int s) {
    const int buf = s % 3;
    const int r = wid * 16 + r16;     // 0..79
    const int c0 = (2 * khalf) ^ (r & 7);
    const int c1 = (2 * khalf + 1) ^ (r & 7);
    const floatx4 f0 = *(const floatx4*)&ldsA[buf * 2560 + r * 32 + c0 * 4];
    const floatx4 f1 = *(const floatx4*)&ldsA[buf * 2560 + r * 32 + c1 * 4];
    union { short8 s8; uint32_t u[4]; } af;
    af.u[0] = pack2(f0.x, f0.y);
    af.u[1] = pack2(f0.z, f0.w);
    af.u[2] = pack2(f1.x, f1.y);
    af.u[3] = pack2(f1.z, f1.w);
    const int bcol = (khalf ^ ((r16 >> 1) & 3)) << 3;  // (erow>>1)&3 == (r16>>1)&3
#pragma unroll
    for (int n = 0; n < NKK; n++) {
      const int erow = n * 16 + r16;
      const short8 bfrag = *(const short8*)&ldsB[buf * 6656 + erow * 32 + bcol];
      acc[n] = __builtin_amdgcn_mfma_f32_16x16x32_bf16(af.s8, bfrag, acc[n], 0, 0, 0);
    }
  };

  stage(0, 0);
  stage(1, 1);

  for (int s = 0; s < 15; s++) {
    VMCNT_BARRIER(4);                 // >= stage(s) landed for every wave
    if (s + 2 < 16) stage((s + 2) % 3, s + 2);
    compute(s);
  }
  VMCNT_BARRIER(0);
  compute(15);

  __syncthreads();   // all LDS reads done; reuse smem as bounce

  // Epilogue 1: bias + f2bf -> bounce[lr][e]   (lr 0..79)
#pragma unroll
  for (int n = 0; n < NKK; n++) {
    const int e = n * 16 + r16;
    const float bv = (e < EE) ? bias[e] : 0.0f;
#pragma unroll
    for (int rr = 0; rr < 4; rr++) {
      const int lr = wid * 16 + khalf * 4 + rr;
      bounce[lr * BSTRIDE + e] = f2bf(acc[n][rr] + bv);
    }
  }
  __syncthreads();

  // Epilogue 2: 13 n x 80 rows x 2 e-halves = 2080 16B pieces.
  for (int c = tid; c < 2080; c += 320) {
    const int n    = c / 160;
    const int rem  = c - n * 160;
    const int lrow = rem >> 1;
    const int eh   = rem & 1;
    const int gr   = row0 + lrow;
    const short8 piece = *(const short8*)&bounce[lrow * BSTRIDE + n * 16 + eh * 8];
    *(short8*)&pT[((size_t)((gr >> 5) * 13 + n)) * 512 + (size_t)(((eh << 5) | (gr & 31)) * 8)] = piece;
  }
}

// ---------------- Kernel 2: pair kernel — A-in-registers, B-in-LDS (R10, unchanged)
__global__ __launch_bounds__(512, 2) void pair_kernel(const short* __restrict__ xpT,
                                                      const short* __restrict__ ypT,
                                                      float* __restrict__ S) {
  __shared__ __align__(16) char lds[2 * 53248 + 16384];
  float* red = (float*)(lds + 2 * 53248);   // [j 0..15][wj 0..3][64 t] = 16 KB

  const int tid  = threadIdx.x;
  const int lane = tid & 63;
  const int wid  = tid >> 6;       // 0..7
  const int jj2  = wid >> 2;       // j-slot within 2-j group
  const int wj   = wid & 3;        // lt-pair
  const int bid  = blockIdx.x;
  const int i    = bid & 63;
  const int jq   = bid >> 6;
  const int jbase = jq * 16;

  // A global->reg: 2 L-tiles x 13 kk fragments
  short8 a0[NKK], a1[NKK];
  {
    const short* ab0 = xpT + ((size_t)((i * 8 + wj * 2 + 0) * NKK)) * 512 + lane * 8;
    const short* ab1 = xpT + ((size_t)((i * 8 + wj * 2 + 1) * NKK)) * 512 + lane * 8;
#pragma unroll
    for (int kk = 0; kk < NKK; kk++) {
      a0[kk] = *(const short8*)(ab0 + kk * 512);
      a1[kk] = *(const short8*)(ab1 + kk * 512);
    }
  }

  auto stageB = [&](int g) {
    const short* src = ypT + (size_t)(jbase + g * 2) * 26 * 512;
    char* dst = lds + (g & 1) * 53248;
    for (int c = tid; c < 3328; c += 512)
      glds16(src + (size_t)c * 8, dst + c * 16);
  };

  stageB(0);
  __syncthreads();

  for (int g = 0; g < 8; g++) {
    if (g + 1 < 8) stageB(g + 1);

    const int j = g * 2 + jj2;
    const short* bbase = (const short*)(lds + (g & 1) * 53248) +
                         (size_t)(jj2 * 26 * 512) + lane * 8;

    floatx16 accA0n0, accA0n1, accA1n0, accA1n1;
#pragma unroll
    for (int r = 0; r < 16; r++) {
      accA0n0[r] = 0.f; accA0n1[r] = 0.f; accA1n0[r] = 0.f; accA1n1[r] = 0.f;
    }

#pragma unroll
    for (int kk = 0; kk < NKK; kk++) {
      const short8 b0 = *(const short8*)(bbase + (0 * NKK + kk) * 512);
      const short8 b1 = *(const short8*)(bbase + (1 * NKK + kk) * 512);
      accA0n0 = __builtin_amdgcn_mfma_f32_32x32x16_bf16(a0[kk], b0, accA0n0, 0, 0, 0);
      accA1n0 = __builtin_amdgcn_mfma_f32_32x32x16_bf16(a1[kk], b0, accA1n0, 0, 0, 0);
      accA0n1 = __builtin_amdgcn_mfma_f32_32x32x16_bf16(a0[kk], b1, accA0n1, 0, 0, 0);
      accA1n1 = __builtin_amdgcn_mfma_f32_32x32x16_bf16(a1[kk], b1, accA1n1, 0, 0, 0);
    }

    float v0 = accA0n0[0], v1 = accA0n1[0];
#pragma unroll
    for (int r = 0; r < 16; r++) {
      v0 = fmaxf(v0, accA0n0[r]); v0 = fmaxf(v0, accA1n0[r]);
      v1 = fmaxf(v1, accA0n1[r]); v1 = fmaxf(v1, accA1n1[r]);
    }
    v0 = fmaxf(v0, __shfl_xor(v0, 32, 64));
    v1 = fmaxf(v1, __shfl_xor(v1, 32, 64));
    if (lane < 32) {
      red[(j * 4 + wj) * 64 + 0 * 32 + lane] = v0;
      red[(j * 4 + wj) * 64 + 1 * 32 + lane] = v1;
    }

    __syncthreads();
  }

  // Final: wave w reduces j = 2w, 2w+1
#pragma unroll
  for (int rep = 0; rep < 2; rep++) {
    const int j = wid * 2 + rep;
    const int t = lane;
    float v = red[(j * 4 + 0) * 64 + t];
    v = fmaxf(v, red[(j * 4 + 1) * 64 + t]);
    v = fmaxf(v, red[(j * 4 + 2) * 64 + t]);
    v = fmaxf(v, red[(j * 4 + 3) * 64 + t]);
    v += __shfl_xor(v, 1, 64);
    v += __shfl_xor(v, 2, 64);
    v += __shfl_xor(v, 4, 64);
    v += __shfl_xor(v, 8, 64);
    v += __shfl_xor(v, 16, 64);
    v += __shfl_xor(v, 32, 64);
    if (t == 0) S[i * BB + jbase + j] = v * (1.0f / 64.0f);
  }
}

extern "C" void kernel_launch(void* const* d_in, const int* in_sizes, int n_in,
                              void* d_out, int out_size, void* d_ws, size_t ws_size,
                              hipStream_t stream) {
  const float* x = (const float*)d_in[0];   // 64*256*512
  const float* y = (const float*)d_in[1];   // 64*64*512
  const float* W = (const float*)d_in[2];   // 200*512
  const float* b = (const float*)d_in[3];   // 200
  float* S = (float*)d_out;                 // 64*64

  char* ws = (char*)d_ws;
  short* Wb = (short*)ws;                   // 208*512*2 = 212,992 B
  short* pT = (short*)(ws + 262144);        // 8320 chunks * 1024 B = 8,519,680 B
  short* ypT = pT + (size_t)6656 * 512;     // y starts at chunk 6656

  wcvt_kernel<<<52, 256, 0, stream>>>(W, Wb);
  proj_kernel<<<256, 320, 0, stream>>>(x, y, Wb, b, pT);
  pair_kernel<<<256, 512, 0, stream>>>(pT, ypT, S);
}

// Round 16
// 44.957 us; speedup vs baseline: 1.0972x; 1.0105x over previous
//
#include <hip/hip_runtime.h>
#include <hip/hip_bf16.h>
#include <stdint.h>

// Problem constants
#define BB 64      // batch
#define LL 256     // x seq len
#define TT 64      // y seq len
#define DD 512     // input dim
#define EE 200     // embed dim
#define EP 208     // embed dim padded to 13*16
#define NKK 13     // K-steps in pair kernel (EP/16)
#define NROWS_X 16384   // 64*256
// Fragment-chunk layout: 1 chunk = 32 rows x 16 e = 64 lanes x 16 B = 1024 B.
// lane l holds row (l&31), e_local (l>>5)*8 .. +8, at shorts chunk*512 + l*8.
// Unified pT: chunk index = (global_row >> 5)*13 + n (x rows first, then y).
#define BSTRIDE 264                // proj bounce row stride in shorts
#define PBM 80                     // proj rows per block: 20480/80 = 256 = exact grid

typedef __attribute__((ext_vector_type(8))) short short8;
typedef __attribute__((ext_vector_type(4))) float floatx4;
typedef __attribute__((ext_vector_type(16))) float floatx16;

__device__ __forceinline__ short f2bf(float f) {
  uint32_t u = __builtin_bit_cast(uint32_t, f);
  u = (u + 0x7fffu + ((u >> 16) & 1u)) >> 16;  // RNE
  return (short)u;
}

__device__ __forceinline__ uint32_t pack2(float lo, float hi) {
  return __builtin_amdgcn_perm(__builtin_bit_cast(uint32_t, hi),
                               __builtin_bit_cast(uint32_t, lo), 0x07060302u);
}

typedef const __attribute__((address_space(1))) uint32_t gu32_t;
typedef __attribute__((address_space(3))) uint32_t lu32_t;
__device__ __forceinline__ void glds16(const void* g, void* l) {
  __builtin_amdgcn_global_load_lds((gu32_t*)g, (lu32_t*)l, 16, 0, 0);
}

// counted-vmcnt barrier. vmcnt is PER-WAVE: every wave must issue the same
// number of glds per stage (here 2) for the count to mean "previous stage
// fully landed" on all waves.
#define VMCNT_BARRIER(N) asm volatile("s_waitcnt vmcnt(" #N ") lgkmcnt(0)\n\ts_barrier" ::: "memory")

// ---------------- Kernel 0: W (200x512 f32) -> Wb (208x512 bf16, zero-padded), RNE
__global__ void wcvt_kernel(const float* __restrict__ W, short* __restrict__ Wb) {
  const int t = blockIdx.x * 256 + threadIdx.x;   // 0 .. 13311
  const int base = t * 8;
  const int e = base >> 9;
  short8 o;
  if (e < EE) {
    const floatx4 f0 = *(const floatx4*)(W + base);
    const floatx4 f1 = *(const floatx4*)(W + base + 4);
    o[0] = f2bf(f0.x); o[1] = f2bf(f0.y); o[2] = f2bf(f0.z); o[3] = f2bf(f0.w);
    o[4] = f2bf(f1.x); o[5] = f2bf(f1.y); o[6] = f2bf(f1.z); o[7] = f2bf(f1.w);
  } else {
    o = (short8)0;
  }
  *(short8*)(Wb + base) = o;
}

// ---------------- Kernel 1: projection GEMM -> fragment-layout pT
// BM=80, grid 256 exact. 960 thr = 15 waves = 3.75 waves/SIMD (R15 was 1.25 —
// the ds_read latency-hiding fix). Wave = (mw 0..4: 16-row tile) x (eh 0..2:
// E-third, 5/4/4 n-tiles). Triple-buffered glds, UNIFORM 2 glds/thread
// (1920 chunk-slots: A 640 + B 832 + 448 benign same-data dups; all split
// points at wave boundaries) -> VMCNT_BARRIER(2).
__global__ __launch_bounds__(960, 1) void proj_kernel(const float* __restrict__ x,
                                                      const float* __restrict__ y,
                                                      const short* __restrict__ Wb,
                                                      const float* __restrict__ bias,
                                                      short* __restrict__ pT) {
  __shared__ __align__(16) char smem[70656];
  float* ldsA = (float*)smem;               // [3][80*32] f32  30,720 B
  short* ldsB = (short*)(smem + 30720);     // [3][208*32] bf16 39,936 B
  short* bounce = (short*)smem;             // [80][BSTRIDE] 42,240 B (after loop)

  const int tid  = threadIdx.x;
  const int lane = tid & 63;
  const int wid  = tid >> 6;          // 0..14
  const int r16   = lane & 15;
  const int khalf = lane >> 4;        // 0..3
  const int mw = wid % 5;             // M-tile (16 rows)
  const int eh = wid / 5;             // E-third
  const int nbase = (eh == 0) ? 0 : (eh == 1) ? 5 : 9;
  const int ncnt  = (eh == 0) ? 5 : 4;

  const int row0 = blockIdx.x * PBM;

  floatx4 acc[5];
#pragma unroll
  for (int n = 0; n < 5; n++) acc[n] = (floatx4){0.f, 0.f, 0.f, 0.f};

  // Stage K-step ks into buffer buf: exactly 2 glds/thread, wave-uniform.
  // A chunk a (0..639): ldsA[r= a>>3][c= a&7] <- src(r)[ks*32 + (c^(r&7))*4]
  // B chunk q (0..831): ldsB[r= q>>2][c= q&3] <- Wb[r][ks*32 + (c^((r>>1)&3))*8]
  // glds#1: tid<640 -> A[tid]; else B[tid-640]          (split @ wave 10)
  // glds#2: tid<512 -> B[tid+320]; else B[tid-512]      (split @ wave 8; dups benign)
  auto stage = [&](int buf, int ks) {
    {
      if (tid < 640) {
        const int a = tid;
        const int r = a >> 3, c = a & 7;
        const int gr = row0 + r;
        const float* src = (gr < NROWS_X) ? (x + (size_t)gr * DD)
                                          : (y + (size_t)(gr - NROWS_X) * DD);
        glds16(src + ks * 32 + ((c ^ (r & 7)) << 2),
               &ldsA[buf * 2560 + a * 4]);
      } else {
        const int q = tid - 640;
        const int r = q >> 2, c = q & 3;
        glds16(Wb + (size_t)r * DD + ks * 32 + ((c ^ ((r >> 1) & 3)) << 3),
               &ldsB[buf * 6656 + q * 8]);
      }
    }
    {
      const int q = (tid < 512) ? (tid + 320) : (tid - 512);
      const int r = q >> 2, c = q & 3;
      glds16(Wb + (size_t)r * DD + ks * 32 + ((c ^ ((r >> 1) & 3)) << 3),
             &ldsB[buf * 6656 + q * 8]);
    }
  };

  auto compute = [&](int s) {
    const int buf = s % 3;
    const int r = mw * 16 + r16;      // 0..79
    const int c0 = (2 * khalf) ^ (r & 7);
    const int c1 = (2 * khalf + 1) ^ (r & 7);
    const floatx4 f0 = *(const floatx4*)&ldsA[buf * 2560 + r * 32 + c0 * 4];
    const floatx4 f1 = *(const floatx4*)&ldsA[buf * 2560 + r * 32 + c1 * 4];
    union { short8 s8; uint32_t u[4]; } af;
    af.u[0] = pack2(f0.x, f0.y);
    af.u[1] = pack2(f0.z, f0.w);
    af.u[2] = pack2(f1.x, f1.y);
    af.u[3] = pack2(f1.z, f1.w);
    const int bcol = (khalf ^ ((r16 >> 1) & 3)) << 3;  // (erow>>1)&3 == (r16>>1)&3
#pragma unroll
    for (int n = 0; n < 5; n++) {
      if (n < ncnt) {
        const int erow = (nbase + n) * 16 + r16;
        const short8 bfrag = *(const short8*)&ldsB[buf * 6656 + erow * 32 + bcol];
        acc[n] = __builtin_amdgcn_mfma_f32_16x16x32_bf16(af.s8, bfrag, acc[n], 0, 0, 0);
      }
    }
  };

  stage(0, 0);
  stage(1, 1);

  for (int s = 0; s < 15; s++) {
    VMCNT_BARRIER(2);                 // stage(s) landed on every wave
    if (s + 2 < 16) stage((s + 2) % 3, s + 2);
    compute(s);
  }
  VMCNT_BARRIER(0);
  compute(15);

  __syncthreads();   // all LDS reads done; reuse smem as bounce

  // Epilogue 1: bias + f2bf -> bounce[lr][e]  (15 waves tile 80 rows x 13 n exactly)
  for (int n = 0; n < ncnt; n++) {
    const int e = (nbase + n) * 16 + r16;
    const float bv = (e < EE) ? bias[e] : 0.0f;
#pragma unroll
    for (int rr = 0; rr < 4; rr++) {
      const int lr = mw * 16 + khalf * 4 + rr;
      bounce[lr * BSTRIDE + e] = f2bf(acc[n][rr] + bv);
    }
  }
  __syncthreads();

  // Epilogue 2: 13 n x 80 rows x 2 e-halves = 2080 16B pieces.
  for (int c = tid; c < 2080; c += 960) {
    const int n    = c / 160;
    const int rem  = c - n * 160;
    const int lrow = rem >> 1;
    const int ehh  = rem & 1;
    const int gr   = row0 + lrow;
    const short8 piece = *(const short8*)&bounce[lrow * BSTRIDE + n * 16 + ehh * 8];
    *(short8*)&pT[((size_t)((gr >> 5) * 13 + n)) * 512 + (size_t)(((ehh << 5) | (gr & 31)) * 8)] = piece;
  }
}

// ---------------- Kernel 2: pair kernel — A-in-registers, B-in-LDS (R10, unchanged)
__global__ __launch_bounds__(512, 2) void pair_kernel(const short* __restrict__ xpT,
                                                      const short* __restrict__ ypT,
                                                      float* __restrict__ S) {
  __shared__ __align__(16) char lds[2 * 53248 + 16384];
  float* red = (float*)(lds + 2 * 53248);   // [j 0..15][wj 0..3][64 t] = 16 KB

  const int tid  = threadIdx.x;
  const int lane = tid & 63;
  const int wid  = tid >> 6;       // 0..7
  const int jj2  = wid >> 2;       // j-slot within 2-j group
  const int wj   = wid & 3;        // lt-pair
  const int bid  = blockIdx.x;
  const int i    = bid & 63;
  const int jq   = bid >> 6;
  const int jbase = jq * 16;

  // A global->reg: 2 L-tiles x 13 kk fragments
  short8 a0[NKK], a1[NKK];
  {
    const short* ab0 = xpT + ((size_t)((i * 8 + wj * 2 + 0) * NKK)) * 512 + lane * 8;
    const short* ab1 = xpT + ((size_t)((i * 8 + wj * 2 + 1) * NKK)) * 512 + lane * 8;
#pragma unroll
    for (int kk = 0; kk < NKK; kk++) {
      a0[kk] = *(const short8*)(ab0 + kk * 512);
      a1[kk] = *(const short8*)(ab1 + kk * 512);
    }
  }

  auto stageB = [&](int g) {
    const short* src = ypT + (size_t)(jbase + g * 2) * 26 * 512;
    char* dst = lds + (g & 1) * 53248;
    for (int c = tid; c < 3328; c += 512)
      glds16(src + (size_t)c * 8, dst + c * 16);
  };

  stageB(0);
  __syncthreads();

  for (int g = 0; g < 8; g++) {
    if (g + 1 < 8) stageB(g + 1);

    const int j = g * 2 + jj2;
    const short* bbase = (const short*)(lds + (g & 1) * 53248) +
                         (size_t)(jj2 * 26 * 512) + lane * 8;

    floatx16 accA0n0, accA0n1, accA1n0, accA1n1;
#pragma unroll
    for (int r = 0; r < 16; r++) {
      accA0n0[r] = 0.f; accA0n1[r] = 0.f; accA1n0[r] = 0.f; accA1n1[r] = 0.f;
    }

#pragma unroll
    for (int kk = 0; kk < NKK; kk++) {
      const short8 b0 = *(const short8*)(bbase + (0 * NKK + kk) * 512);
      const short8 b1 = *(const short8*)(bbase + (1 * NKK + kk) * 512);
      accA0n0 = __builtin_amdgcn_mfma_f32_32x32x16_bf16(a0[kk], b0, accA0n0, 0, 0, 0);
      accA1n0 = __builtin_amdgcn_mfma_f32_32x32x16_bf16(a1[kk], b0, accA1n0, 0, 0, 0);
      accA0n1 = __builtin_amdgcn_mfma_f32_32x32x16_bf16(a0[kk], b1, accA0n1, 0, 0, 0);
      accA1n1 = __builtin_amdgcn_mfma_f32_32x32x16_bf16(a1[kk], b1, accA1n1, 0, 0, 0);
    }

    float v0 = accA0n0[0], v1 = accA0n1[0];
#pragma unroll
    for (int r = 0; r < 16; r++) {
      v0 = fmaxf(v0, accA0n0[r]); v0 = fmaxf(v0, accA1n0[r]);
      v1 = fmaxf(v1, accA0n1[r]); v1 = fmaxf(v1, accA1n1[r]);
    }
    v0 = fmaxf(v0, __shfl_xor(v0, 32, 64));
    v1 = fmaxf(v1, __shfl_xor(v1, 32, 64));
    if (lane < 32) {
      red[(j * 4 + wj) * 64 + 0 * 32 + lane] = v0;
      red[(j * 4 + wj) * 64 + 1 * 32 + lane] = v1;
    }

    __syncthreads();
  }

  // Final: wave w reduces j = 2w, 2w+1
#pragma unroll
  for (int rep = 0; rep < 2; rep++) {
    const int j = wid * 2 + rep;
    const int t = lane;
    float v = red[(j * 4 + 0) * 64 + t];
    v = fmaxf(v, red[(j * 4 + 1) * 64 + t]);
    v = fmaxf(v, red[(j * 4 + 2) * 64 + t]);
    v = fmaxf(v, red[(j * 4 + 3) * 64 + t]);
    v += __shfl_xor(v, 1, 64);
    v += __shfl_xor(v, 2, 64);
    v += __shfl_xor(v, 4, 64);
    v += __shfl_xor(v, 8, 64);
    v += __shfl_xor(v, 16, 64);
    v += __shfl_xor(v, 32, 64);
    if (t == 0) S[i * BB + jbase + j] = v * (1.0f / 64.0f);
  }
}

extern "C" void kernel_launch(void* const* d_in, const int* in_sizes, int n_in,
                              void* d_out, int out_size, void* d_ws, size_t ws_size,
                              hipStream_t stream) {
  const float* x = (const float*)d_in[0];   // 64*256*512
  const float* y = (const float*)d_in[1];   // 64*64*512
  const float* W = (const float*)d_in[2];   // 200*512
  const float* b = (const float*)d_in[3];   // 200
  float* S = (float*)d_out;                 // 64*64

  char* ws = (char*)d_ws;
  short* Wb = (short*)ws;                   // 208*512*2 = 212,992 B
  short* pT = (short*)(ws + 262144);        // 8320 chunks * 1024 B = 8,519,680 B
  short* ypT = pT + (size_t)6656 * 512;     // y starts at chunk 6656

  wcvt_kernel<<<52, 256, 0, stream>>>(W, Wb);
  proj_kernel<<<256, 960, 0, stream>>>(x, y, Wb, b, pT);
  pair_kernel<<<256, 512, 0, stream>>>(pT, ypT, S);
}